// Round 1
// baseline (83.759 us; speedup 1.0000x reference)
//
#include <hip/hip_runtime.h>
#include <math.h>
#include <stdint.h>

#define N_QUBITS 4
#define N_LAYERS 6
#define NW (N_LAYERS * N_QUBITS)

// POD 4-float vector (no C++ ctors -> safe across address spaces)
typedef float vfloat4 __attribute__((ext_vector_type(4)));

// ---------------------------------------------------------------------------
// Prep kernel (1 block): build W (16x16 complex) from the 24 RX gates + CNOT
// rings, form S_q = Re(W^dag Z_q W), contract to the 81-term multilinear table
//   out_q(x) = sum_{t in {I,Z,X}^4} C_q[t] * prod_p (1, cos x_p, sin x_p)[t_p]
// Layout: Ctab[t*4 + q]  (float4 per term t -> one load feeds all 4 outputs).
// (unchanged — single-variable experiment on the eval side)
// ---------------------------------------------------------------------------
__global__ __launch_bounds__(256) void qprep_kernel(
    const float* __restrict__ weights, float* __restrict__ Ctab)
{
    __shared__ float Wr[16][16];
    __shared__ float Wi[16][16];
    __shared__ float S[4][16][16];
    __shared__ float wc[NW], ws[NW];
    const int tid = threadIdx.x;
    if (tid < NW) {
        float t = weights[tid] * 0.5f;
        wc[tid] = __cosf(t);
        ws[tid] = __sinf(t);
    }
    __syncthreads();

    // Phase 1: threads 0..15 build column `tid` of W
    if (tid < 16) {
        float re[16], im[16];
#pragma unroll
        for (int k = 0; k < 16; ++k) { re[k] = (k == tid) ? 1.f : 0.f; im[k] = 0.f; }
#pragma unroll 1
        for (int l = 0; l < N_LAYERS; ++l) {
#pragma unroll
            for (int q = 0; q < 4; ++q) {
                const float ct = wc[l * 4 + q], sn = ws[l * 4 + q];
                const int mask = 8 >> q;
#pragma unroll
                for (int idx = 0; idx < 16; ++idx) {
                    if (idx & mask) continue;
                    const int j = idx | mask;
                    float r0 = re[idx], u0 = im[idx], r1 = re[j], u1 = im[j];
                    re[idx] = ct * r0 + sn * u1; im[idx] = ct * u0 - sn * r1;
                    re[j]   = ct * r1 + sn * u0; im[j]   = ct * u1 - sn * r0;
                }
            }
#pragma unroll
            for (int q = 0; q < 4; ++q) {
                const int cm = 8 >> q, tm = 8 >> ((q + 1) & 3);
#pragma unroll
                for (int idx = 0; idx < 16; ++idx) {
                    if ((idx & cm) && !(idx & tm)) {
                        const int j = idx | tm;
                        float t0 = re[idx]; re[idx] = re[j]; re[j] = t0;
                        float t1 = im[idx]; im[idx] = im[j]; im[j] = t1;
                    }
                }
            }
        }
#pragma unroll
        for (int k = 0; k < 16; ++k) { Wr[k][tid] = re[k]; Wi[k][tid] = im[k]; }
    }
    __syncthreads();

    // Phase 2: thread (i,j): S_q[i][j] = sum_k z_q(k) Re(W[k,i] conj(W[k,j]))
    {
        const int i = tid >> 4, j = tid & 15;
        float acc0 = 0.f, acc1 = 0.f, acc2 = 0.f, acc3 = 0.f;
#pragma unroll
        for (int k = 0; k < 16; ++k) {
            const float prod = Wr[k][i] * Wr[k][j] + Wi[k][i] * Wi[k][j];
            acc0 += (k & 8) ? -prod : prod;
            acc1 += (k & 4) ? -prod : prod;
            acc2 += (k & 2) ? -prod : prod;
            acc3 += (k & 1) ? -prod : prod;
        }
        S[0][i][j] = acc0; S[1][i][j] = acc1; S[2][i][j] = acc2; S[3][i][j] = acc3;
    }
    __syncthreads();

    // Phase 3: C_q[t] = (1/16) sum_i (-1)^popc(i&zm) S_q[i][i^xm]
    if (tid < 81) {
        const int t1 = tid / 27, t2 = (tid / 9) % 3, t3 = (tid / 3) % 3, t4 = tid % 3;
        int zm = 0, xm = 0;
        if (t1 == 1) zm |= 8; else if (t1 == 2) xm |= 8;
        if (t2 == 1) zm |= 4; else if (t2 == 2) xm |= 4;
        if (t3 == 1) zm |= 2; else if (t3 == 2) xm |= 2;
        if (t4 == 1) zm |= 1; else if (t4 == 2) xm |= 1;
#pragma unroll
        for (int q = 0; q < 4; ++q) {
            float acc = 0.f;
#pragma unroll
            for (int i = 0; i < 16; ++i) {
                const float v = S[q][i][i ^ xm];
                acc += (__popc(i & zm) & 1) ? -v : v;
            }
            Ctab[tid * 4 + q] = acc * 0.0625f;   // float4-per-term layout
        }
    }
}

// ---------------------------------------------------------------------------
// Main kernel: out4 = sum_i u9[i] * ( sum_j C4[i*9+j] * w9[j] ).
// KEY CHANGE vs R9: coefficient table staged into LDS once per block
// (81 x float4 = 1.3 KB), read with uniform-address ds_read_b128.
// Same-address LDS access is a HW broadcast: one 16 B bank fetch serves all
// 64 lanes, no bank conflict. This deterministically removes the 83 KB/wave
// per-lane broadcast return traffic through L1 (81 float4 x 64 lanes) that
// pinned qeval at ~18 us across R2/R5/R6/R8 — and does NOT depend on the
// compiler's scalar-load (s_load) selection, which the R9 AS(4) cast
// apparently failed to trigger (total was unchanged).
// x-load is hoisted above the staging barrier so HBM latency hides under
// __syncthreads.
// ---------------------------------------------------------------------------
__global__ __launch_bounds__(256, 6) void qeval_kernel(
    const float* __restrict__ x, const float* __restrict__ Ctab,
    float* __restrict__ out, int B)
{
    __shared__ vfloat4 Cs[81];

    int b = blockIdx.x * 256 + threadIdx.x;
    b = (b < B) ? b : (B - 1);   // clamp: wave-uniform control flow

    // Issue the per-thread x load first (hides under the staging barrier).
    const float4 xv = reinterpret_cast<const float4*>(x)[b];

    // Stage coefficient table into LDS (one float4 per thread, 81 threads).
    if (threadIdx.x < 81) {
        Cs[threadIdx.x] = reinterpret_cast<const vfloat4*>(Ctab)[threadIdx.x];
    }
    __syncthreads();

    const float c0 = __cosf(xv.x), s0 = __sinf(xv.x);
    const float c1 = __cosf(xv.y), s1 = __sinf(xv.y);
    const float c2 = __cosf(xv.z), s2 = __sinf(xv.z);
    const float c3 = __cosf(xv.w), s3 = __sinf(xv.w);

    // u9[t1*3+t2] = v0[t1]*v1[t2];  w9[t3*3+t4] = v2[t3]*v3[t4]
    float u9[9], w9[9];
    u9[0] = 1.f;  u9[1] = c1;      u9[2] = s1;
    u9[3] = c0;   u9[4] = c0 * c1; u9[5] = c0 * s1;
    u9[6] = s0;   u9[7] = s0 * c1; u9[8] = s0 * s1;
    w9[0] = 1.f;  w9[1] = c3;      w9[2] = s3;
    w9[3] = c2;   w9[4] = c2 * c3; w9[5] = c2 * s3;
    w9[6] = s2;   w9[7] = s2 * c3; w9[8] = s2 * s3;

    float4 o = make_float4(0.f, 0.f, 0.f, 0.f);
#pragma unroll
    for (int i = 0; i < 9; ++i) {
        float4 t = make_float4(0.f, 0.f, 0.f, 0.f);
#pragma unroll
        for (int j = 0; j < 9; ++j) {
            const vfloat4 c = Cs[i * 9 + j];   // uniform addr -> LDS broadcast
            const float w = w9[j];
            t.x = fmaf(c.x, w, t.x);
            t.y = fmaf(c.y, w, t.y);
            t.z = fmaf(c.z, w, t.z);
            t.w = fmaf(c.w, w, t.w);
        }
        const float u = u9[i];
        o.x = fmaf(t.x, u, o.x);
        o.y = fmaf(t.y, u, o.y);
        o.z = fmaf(t.z, u, o.z);
        o.w = fmaf(t.w, u, o.w);
    }

    reinterpret_cast<float4*>(out)[b] = o;
}

extern "C" void kernel_launch(void* const* d_in, const int* in_sizes, int n_in,
                              void* d_out, int out_size, void* d_ws, size_t ws_size,
                              hipStream_t stream) {
    const float* x = (const float*)d_in[0];
    const float* weights = (const float*)d_in[1];
    float* out = (float*)d_out;
    float* Ctab = (float*)d_ws;   // 324 floats, float4-per-term
    const int B = in_sizes[0] / 4;

    qprep_kernel<<<1, 256, 0, stream>>>(weights, Ctab);

    const int grid = (B + 255) / 256;
    qeval_kernel<<<grid, 256, 0, stream>>>(x, Ctab, out, B);
}